// Round 5
// baseline (720.999 us; speedup 1.0000x reference)
//
#include <hip/hip_runtime.h>

typedef unsigned int uint;
typedef unsigned short ushort_t;
typedef __bf16 bf16x8 __attribute__((ext_vector_type(8)));
typedef float f32x4 __attribute__((ext_vector_type(4)));

__device__ __forceinline__ int imin(int a, int b){ return a<b?a:b; }
__device__ __forceinline__ int imax(int a, int b){ return a>b?a:b; }

__device__ __forceinline__ ushort_t f2b(float f){
  uint u = __builtin_bit_cast(uint, f);
  u += 0x7FFFu + ((u>>16)&1u);          // round-to-nearest-even
  return (ushort_t)(u>>16);
}
__device__ __forceinline__ float b2f(ushort_t s){
  uint u = ((uint)s)<<16;
  return __builtin_bit_cast(float, u);
}
__device__ __forceinline__ f32x4 fz4(){ f32x4 z; z[0]=0.f; z[1]=0.f; z[2]=0.f; z[3]=0.f; return z; }

// async global->LDS, 16 B per lane. LDS dest = wave-uniform base + lane*16.
__device__ __forceinline__ void gload16(const void* g, void* lds){
  __builtin_amdgcn_global_load_lds(
      (const __attribute__((address_space(1))) void*)g,
      (__attribute__((address_space(3))) void*)lds,
      16, 0, 0);
}

// ---------------- fp32 -> bf16 pre-convert (activations + QKV weights) ----
struct CJob { const float* src; ushort_t* dst; int nvec; };  // nvec = elems/8

__global__ __launch_bounds__(256) void convert_k(CJob j0, CJob j1, CJob j2,
                                                 CJob j3, CJob j4, CJob j5)
{
  CJob jb;
  switch (blockIdx.y){
    case 0: jb=j0; break; case 1: jb=j1; break; case 2: jb=j2; break;
    case 3: jb=j3; break; case 4: jb=j4; break; default: jb=j5; break;
  }
  int stride = gridDim.x*256;
  for (int i = blockIdx.x*256 + threadIdx.x; i < jb.nvec; i += stride){
    const float4* s = (const float4*)(jb.src + (size_t)i*8);
    float4 v0 = s[0], v1 = s[1];
    uint4 pk;
    pk.x = (uint)f2b(v0.x) | ((uint)f2b(v0.y)<<16);
    pk.y = (uint)f2b(v0.z) | ((uint)f2b(v0.w)<<16);
    pk.z = (uint)f2b(v1.x) | ((uint)f2b(v1.y)<<16);
    pk.w = (uint)f2b(v1.z) | ((uint)f2b(v1.w)<<16);
    *(uint4*)(jb.dst + (size_t)i*8) = pk;
  }
}

// ---------------- GEMM (QKV): C[M,N] = A[M,K] @ W[N,K]^T + bias ----------
// M=4096, N=1024, K=1024. 128x128 tile, BK=32, 256 threads (4 waves, 64x64).
// Staging via global_load_lds (16B/lane, linear LDS dest). Bank-conflict-free
// fragment reads via XOR swizzle on the GLOBAL source col (rule 21) + same
// XOR on the ds_read address.
struct GArg { const ushort_t* A; const ushort_t* W; const float* bias; void* O; };

__global__ __launch_bounds__(256) void gemm_nt(GArg g0, GArg g1, GArg g2)
{
  GArg g = (blockIdx.z==0) ? g0 : ((blockIdx.z==1) ? g1 : g2);
  __shared__ __align__(16) ushort_t As[128*32];
  __shared__ __align__(16) ushort_t Bs[128*32];
  const int tid  = threadIdx.x;
  const int lane = tid & 63;
  const int w    = tid >> 6;
  const int ml   = lane & 15, quad = lane >> 4;

  // XCD-aware block swizzle: 256 wgs per z-slice, 256%8==0 -> bijective.
  int lid = blockIdx.x + 8*blockIdx.y;
  int t   = (lid & 7)*32 + (lid >> 3);
  const int m0 = (t >> 3)*128, n0 = (t & 7)*128;
  const int wm = (w>>1)*64, wn = (w&1)*64;

  const int srow = lane >> 2;                           // 0..15
  const int scol = ((lane & 3) ^ ((lane >> 3) & 3))*8;  // pre-swizzled col
  const int rA0 = w*16, rA1 = 64 + w*16;
  const ushort_t* gA = g.A + (size_t)m0*1024;
  const ushort_t* gB = g.W + (size_t)n0*1024;
  const int sxor = (quad ^ ((ml >> 1) & 3))*8;

  f32x4 acc[4][4];
  #pragma unroll
  for (int i=0;i<4;i++)
    #pragma unroll
    for (int j=0;j<4;j++) acc[i][j]=fz4();

  for (int kt=0; kt<32; ++kt){
    int kof = kt*32 + scol;
    gload16(gA + (size_t)(rA0+srow)*1024 + kof, &As[rA0*32]);
    gload16(gA + (size_t)(rA1+srow)*1024 + kof, &As[rA1*32]);
    gload16(gB + (size_t)(rA0+srow)*1024 + kof, &Bs[rA0*32]);
    gload16(gB + (size_t)(rA1+srow)*1024 + kof, &Bs[rA1*32]);
    __syncthreads();

    bf16x8 af[4], bfr[4];
    #pragma unroll
    for (int t4=0;t4<4;t4++)
      af[t4]  = __builtin_bit_cast(bf16x8, *(const uint4*)&As[(wm + t4*16 + ml)*32 + sxor]);
    #pragma unroll
    for (int t4=0;t4<4;t4++)
      bfr[t4] = __builtin_bit_cast(bf16x8, *(const uint4*)&Bs[(wn + t4*16 + ml)*32 + sxor]);
    #pragma unroll
    for (int ti=0;ti<4;ti++)
      #pragma unroll
      for (int tj=0;tj<4;tj++)
        acc[ti][tj] = __builtin_amdgcn_mfma_f32_16x16x32_bf16(af[ti], bfr[tj], acc[ti][tj], 0,0,0);
    __syncthreads();
  }
  // ---- epilogue: C row=(lane>>4)*4+reg, col=lane&15 (m89-verified) ----
  #pragma unroll
  for (int tj=0;tj<4;tj++){
    int gcol = n0 + wn + tj*16 + ml;
    float bv = g.bias[gcol];
    #pragma unroll
    for (int ti=0;ti<4;ti++){
      int growb = m0 + wm + ti*16 + quad*4;
      #pragma unroll
      for (int r=0;r<4;r++){
        float val = acc[ti][tj][r] + bv;
        ((ushort_t*)g.O)[(size_t)(growb + r)*1024 + gcol] = f2b(val);
      }
    }
  }
}

// ---------------- GEMM (out-proj): O[M,N] = A[M,K] @ W[N,K]^T + bias ------
// 128x64 tile -> 512 wgs = 2 wgs/CU (vs 1 for 128x128): overlaps the barrier
// vmcnt drain across wgs. W is fp32 (Wo): f2b folded into B-staging (removes
// the dependent convert#2 launch). A via global_load_lds as above.
__global__ __launch_bounds__(256) void gemm_out(
    const ushort_t* A, const float* W, const float* bias, float* O)
{
  __shared__ __align__(16) ushort_t As[128*32];
  __shared__ __align__(16) ushort_t Bs[64*32];
  const int tid  = threadIdx.x;
  const int lane = tid & 63;
  const int w    = tid >> 6;
  const int ml   = lane & 15, quad = lane >> 4;

  // grid (16,32): lid in [0,512), 512%8==0 -> bijective XCD swizzle
  int lid = blockIdx.x + 16*blockIdx.y;
  int t   = (lid & 7)*64 + (lid >> 3);
  const int m0 = (t >> 4)*128, n0 = (t & 15)*64;
  const int wm = (w>>1)*64, wn = (w&1)*32;

  const int srow = lane >> 2;
  const int scol = ((lane & 3) ^ ((lane >> 3) & 3))*8;
  const int rA0 = w*16, rA1 = 64 + w*16;
  const ushort_t* gA = A + (size_t)m0*1024;
  const int sxor = (quad ^ ((ml >> 1) & 3))*8;

  // B reg-stage mapping: 256 threads = 64 rows x 4 col-chunks (8 fp32 each)
  const int brow = tid >> 2, bc = tid & 3;
  const int bscol = (bc ^ ((brow >> 1) & 3))*8;   // swizzled LDS col (write side)
  const float* gW = W + (size_t)(n0 + brow)*1024 + bc*8;

  f32x4 acc[4][2];
  #pragma unroll
  for (int i=0;i<4;i++){ acc[i][0]=fz4(); acc[i][1]=fz4(); }

  for (int kt=0; kt<32; ++kt){
    int kof = kt*32 + scol;
    gload16(gA + (size_t)(rA0+srow)*1024 + kof, &As[rA0*32]);
    gload16(gA + (size_t)(rA1+srow)*1024 + kof, &As[rA1*32]);
    {
      const float* gw = gW + kt*32;
      float4 v0 = *(const float4*)gw;
      float4 v1 = *(const float4*)(gw+4);
      uint4 pk;
      pk.x = (uint)f2b(v0.x) | ((uint)f2b(v0.y)<<16);
      pk.y = (uint)f2b(v0.z) | ((uint)f2b(v0.w)<<16);
      pk.z = (uint)f2b(v1.x) | ((uint)f2b(v1.y)<<16);
      pk.w = (uint)f2b(v1.z) | ((uint)f2b(v1.w)<<16);
      *(uint4*)&Bs[brow*32 + bscol] = pk;
    }
    __syncthreads();

    bf16x8 af[4], bfr[2];
    #pragma unroll
    for (int t4=0;t4<4;t4++)
      af[t4]  = __builtin_bit_cast(bf16x8, *(const uint4*)&As[(wm + t4*16 + ml)*32 + sxor]);
    #pragma unroll
    for (int t4=0;t4<2;t4++)
      bfr[t4] = __builtin_bit_cast(bf16x8, *(const uint4*)&Bs[(wn + t4*16 + ml)*32 + sxor]);
    #pragma unroll
    for (int ti=0;ti<4;ti++)
      #pragma unroll
      for (int tj=0;tj<2;tj++)
        acc[ti][tj] = __builtin_amdgcn_mfma_f32_16x16x32_bf16(af[ti], bfr[tj], acc[ti][tj], 0,0,0);
    __syncthreads();
  }
  #pragma unroll
  for (int tj=0;tj<2;tj++){
    int gcol = n0 + wn + tj*16 + ml;
    float bv = bias[gcol];
    #pragma unroll
    for (int ti=0;ti<4;ti++){
      int growb = m0 + wm + ti*16 + quad*4;
      #pragma unroll
      for (int r=0;r<4;r++)
        O[(size_t)(growb + r)*1024 + gcol] = acc[ti][tj][r] + bv;
    }
  }
}

// ---------------- sparse attention ----------------
// wg = (b, h, 32 query rows). 128 threads = 2 waves; wave w owns rows 16w..16w+15.
// Slots: 0..255 strided (j=8*slot), 256..351 local (j = i0-32 + slot-256).
#define SW2 360   // row stride in bf16 elems
__global__ __launch_bounds__(128) void attn_k(
    const ushort_t* Qb, const ushort_t* Kb, const ushort_t* Vb,
    ushort_t* Ctxb, float* attn_out)
{
  __shared__ ushort_t stash[32*SW2];   // unnormalized exp(score), bf16
  __shared__ float invl[32];           // 1 / row-sum
  const int lane = threadIdx.x & 63;
  const int w    = threadIdx.x >> 6;
  const int ml   = lane & 15, quad = lane >> 4;
  // XCD swizzle: 2048 wgs, %8==0 bijective; groups tiles of one (b,h) panel.
  int lid = blockIdx.x + 64*(blockIdx.y + 16*blockIdx.z);
  int tt  = (lid & 7)*256 + (lid >> 3);
  const int tile = tt & 63, h = (tt >> 6) & 15, b = tt >> 10;
  const int i0  = tile*32;
  const int jl0 = i0 - 32;
  const int rb  = 16*w;
  const size_t bh = (size_t)b*2048*1024 + (size_t)h*64;

  // ---- phase 1: scores -> exp -> stash; row-sums ----
  bf16x8 aq0, aq1;
  {
    const ushort_t* qp = Qb + bh + (size_t)(i0 + rb + ml)*1024 + quad*8;
    aq0 = __builtin_bit_cast(bf16x8, *(const uint4*)qp);
    aq1 = __builtin_bit_cast(bf16x8, *(const uint4*)(qp + 32));
  }
  float lsum[4] = {0.f,0.f,0.f,0.f};
  for (int c=0;c<22;c++){
    int j  = (c<16) ? (128*c + 8*ml) : (jl0 + 16*(c-16) + ml);
    int jc = imin(imax(j,0),2047);
    const ushort_t* kp = Kb + bh + (size_t)jc*1024 + quad*8;
    bf16x8 kb0 = __builtin_bit_cast(bf16x8, *(const uint4*)kp);
    bf16x8 kb1 = __builtin_bit_cast(bf16x8, *(const uint4*)(kp + 32));
    f32x4 sc = fz4();
    sc = __builtin_amdgcn_mfma_f32_16x16x32_bf16(aq0, kb0, sc, 0,0,0);
    sc = __builtin_amdgcn_mfma_f32_16x16x32_bf16(aq1, kb1, sc, 0,0,0);
    int slot = 16*c + ml;
    #pragma unroll
    for (int r=0;r<4;r++){
      int rl = rb + quad*4 + r;
      int i  = i0 + rl;
      bool valid = (c<16) ? true :
        ((j>=0) && (j<2048) && ((j&7)!=0) && (j >= i-32) && (j < i+32));
      float e = valid ? __expf(sc[r]*0.125f) : 0.f;   // masked -> exact 0
      ushort_t eb = f2b(e);
      lsum[r] += b2f(eb);                 // sum the ROUNDED values
      stash[rl*SW2 + slot] = eb;
    }
  }
  #pragma unroll
  for (int off=1; off<16; off<<=1){
    #pragma unroll
    for (int r=0;r<4;r++) lsum[r] += __shfl_xor(lsum[r], off);
  }
  if (ml==0){
    #pragma unroll
    for (int r=0;r<4;r++) invl[rb + quad*4 + r] = 1.f / lsum[r];
  }
  // No __syncthreads: each wave only ever touches its own 16 rows.

  // ---- phase 2: coalesced dense attn row writes (512 MB stream; nt) ----
  // Per iteration, the 64 lanes cover one 256-elem column segment of row r.
  // The local window occupies slots [jl0, jl0+96): a block-uniform range
  // intersecting only 1-2 of the 8 segments -> uniform fast path otherwise.
  const size_t arow = ((size_t)(b*16 + h))*2048;
  for (int it=0; it<128; ++it){
    int r     = rb + (it>>3);
    int seg   = it & 7;
    int inner = (seg<<6) + lane;        // 512 float4-groups per row
    int j0    = inner*4;
    float inv  = invl[r];
    float sval = b2f(stash[r*SW2 + (inner>>1)]);      // strided slot (iff inner even)
    f32x4 o;
    bool segLocal = (seg*256 < jl0 + 96) && (seg*256 + 256 > jl0);  // uniform
    if (segLocal){
      int off  = j0 - jl0;                            // local-window offset (mult of 4)
      int offc = imin(imax(off,0),92);
      uint2 lvu = *(const uint2*)&stash[r*SW2 + 256 + offc];  // 4 local bf16
      bool lok = (off>=0) && (off<96);
      float lx = lok ? b2f((ushort_t)(lvu.x & 0xffffu)) : 0.f;
      float ly = lok ? b2f((ushort_t)(lvu.x >> 16))     : 0.f;
      float lz = lok ? b2f((ushort_t)(lvu.y & 0xffffu)) : 0.f;
      float lw = lok ? b2f((ushort_t)(lvu.y >> 16))     : 0.f;
      o[0] = ((inner&1)==0) ? inv*sval : inv*lx;      // j%8==0 -> strided value
      o[1] = inv*ly; o[2] = inv*lz; o[3] = inv*lw;
    } else {
      o[0] = ((inner&1)==0) ? inv*sval : 0.f;
      o[1] = 0.f; o[2] = 0.f; o[3] = 0.f;
    }
    __builtin_nontemporal_store(o, (f32x4*)&attn_out[(arow + i0 + r)*2048 + j0]);
  }

  // ---- phase 3: PV via MFMA ----
  f32x4 pacc[4];
  #pragma unroll
  for (int nt=0;nt<4;nt++) pacc[nt]=fz4();
  const ushort_t* prow = &stash[(rb + ml)*SW2];
  for (int ck=0; ck<11; ++ck){
    int s0 = ck*32;
    bf16x8 pa = __builtin_bit_cast(bf16x8, *(const uint4*)(prow + s0 + quad*8));
    ushort_t vr[4][8];
    #pragma unroll
    for (int e=0;e<8;e++){
      int s = s0 + quad*8 + e;
      int j = (s<256) ? 8*s : (jl0 + s - 256);
      int jc = imin(imax(j,0),2047);
      const ushort_t* vp = Vb + bh + (size_t)jc*1024 + ml;
      #pragma unroll
      for (int nt=0;nt<4;nt++) vr[nt][e] = vp[nt*16];
    }
    #pragma unroll
    for (int nt=0;nt<4;nt++){
      uint4 pk;
      pk.x = (uint)vr[nt][0] | ((uint)vr[nt][1]<<16);
      pk.y = (uint)vr[nt][2] | ((uint)vr[nt][3]<<16);
      pk.z = (uint)vr[nt][4] | ((uint)vr[nt][5]<<16);
      pk.w = (uint)vr[nt][6] | ((uint)vr[nt][7]<<16);
      bf16x8 bfr = __builtin_bit_cast(bf16x8, pk);
      pacc[nt] = __builtin_amdgcn_mfma_f32_16x16x32_bf16(pa, bfr, pacc[nt], 0,0,0);
    }
  }
  // D layout: row = quad*4+reg (within wave's 16-row tile), col = nt*16+ml
  #pragma unroll
  for (int nt=0;nt<4;nt++){
    #pragma unroll
    for (int rr=0;rr<4;rr++){
      int r = rb + quad*4 + rr;
      float val = pacc[nt][rr] * invl[r];
      Ctxb[bh + (size_t)(i0 + r)*1024 + nt*16 + ml] = f2b(val);
    }
  }
}

extern "C" void kernel_launch(void* const* d_in, const int* in_sizes, int n_in,
                              void* d_out, int out_size, void* d_ws, size_t ws_size,
                              hipStream_t stream) {
  (void)in_sizes; (void)n_in; (void)out_size; (void)ws_size;
  const float* query = (const float*)d_in[0];
  const float* key_  = (const float*)d_in[1];
  const float* value = (const float*)d_in[2];
  const float* Wq = (const float*)d_in[3];
  const float* bq = (const float*)d_in[4];
  const float* Wk = (const float*)d_in[5];
  const float* bk = (const float*)d_in[6];
  const float* Wv = (const float*)d_in[7];
  const float* bv = (const float*)d_in[8];
  const float* Wo = (const float*)d_in[9];
  const float* bo = (const float*)d_in[10];

  // Workspace: exactly 32 MB (Qb/Kb/Vb/Ctxb, bf16 4096x1024 each).
  char* ws = (char*)d_ws;
  ushort_t* Qb   = (ushort_t*)(ws);
  ushort_t* Kb   = (ushort_t*)(ws + (size_t)( 8<<20));
  ushort_t* Vb   = (ushort_t*)(ws + (size_t)(16<<20));
  ushort_t* Ctxb = (ushort_t*)(ws + (size_t)(24<<20));

  float* out = (float*)d_out;
  float* attn_out = out + (size_t)4096*1024;

  // Scratch: the 512 MB attn_out region is dead until attn_k overwrites it.
  ushort_t* scr = (ushort_t*)attn_out;
  ushort_t* Aq  = scr;
  ushort_t* Ak  = scr + (size_t)1*4096*1024;
  ushort_t* Av  = scr + (size_t)2*4096*1024;
  ushort_t* Wqb = scr + (size_t)3*4096*1024;
  ushort_t* Wkb = Wqb + (size_t)1024*1024;
  ushort_t* Wvb = Wkb + (size_t)1024*1024;

  const int NA = 4096*1024/8;   // 524288 vec8 per activation matrix
  const int NW = 1024*1024/8;   // 131072 vec8 per weight matrix

  CJob ja{query, Aq, NA}, jb{key_, Ak, NA}, jc{value, Av, NA};
  CJob jd{Wq, Wqb, NW}, je{Wk, Wkb, NW}, jf{Wv, Wvb, NW};
  convert_k<<<dim3(1024,6), 256, 0, stream>>>(ja, jb, jc, jd, je, jf);

  GArg ga{Aq, Wqb, bq, Qb};
  GArg gb{Ak, Wkb, bk, Kb};
  GArg gc{Av, Wvb, bv, Vb};
  gemm_nt<<<dim3(8,32,3), 256, 0, stream>>>(ga, gb, gc);

  attn_k<<<dim3(64,16,2), 128, 0, stream>>>(Qb, Kb, Vb, Ctxb, attn_out);

  // out-projection: Wo f2b fused into staging (no convert#2 launch)
  gemm_out<<<dim3(16,32), 256, 0, stream>>>(Ctxb, Wo, bo, out);
}

// Round 6
// 716.676 us; speedup vs baseline: 1.0060x; 1.0060x over previous
//
#include <hip/hip_runtime.h>

typedef unsigned int uint;
typedef unsigned short ushort_t;
typedef __bf16 bf16x8 __attribute__((ext_vector_type(8)));
typedef float f32x4 __attribute__((ext_vector_type(4)));

__device__ __forceinline__ int imin(int a, int b){ return a<b?a:b; }
__device__ __forceinline__ int imax(int a, int b){ return a>b?a:b; }

__device__ __forceinline__ ushort_t f2b(float f){
  uint u = __builtin_bit_cast(uint, f);
  u += 0x7FFFu + ((u>>16)&1u);          // round-to-nearest-even
  return (ushort_t)(u>>16);
}
__device__ __forceinline__ float b2f(ushort_t s){
  uint u = ((uint)s)<<16;
  return __builtin_bit_cast(float, u);
}
__device__ __forceinline__ f32x4 fz4(){ f32x4 z; z[0]=0.f; z[1]=0.f; z[2]=0.f; z[3]=0.f; return z; }

// async global->LDS, 16 B per lane. LDS dest = wave-uniform base + lane*16.
__device__ __forceinline__ void gload16(const void* g, void* lds){
  __builtin_amdgcn_global_load_lds(
      (const __attribute__((address_space(1))) void*)g,
      (__attribute__((address_space(3))) void*)lds,
      16, 0, 0);
}

// ---------------- fp32 -> bf16 pre-convert (activations + QKV weights) ----
struct CJob { const float* src; ushort_t* dst; int nvec; };  // nvec = elems/8

__global__ __launch_bounds__(256) void convert_k(CJob j0, CJob j1, CJob j2,
                                                 CJob j3, CJob j4, CJob j5)
{
  CJob jb;
  switch (blockIdx.y){
    case 0: jb=j0; break; case 1: jb=j1; break; case 2: jb=j2; break;
    case 3: jb=j3; break; case 4: jb=j4; break; default: jb=j5; break;
  }
  int stride = gridDim.x*256;
  for (int i = blockIdx.x*256 + threadIdx.x; i < jb.nvec; i += stride){
    const float4* s = (const float4*)(jb.src + (size_t)i*8);
    float4 v0 = s[0], v1 = s[1];
    uint4 pk;
    pk.x = (uint)f2b(v0.x) | ((uint)f2b(v0.y)<<16);
    pk.y = (uint)f2b(v0.z) | ((uint)f2b(v0.w)<<16);
    pk.z = (uint)f2b(v1.x) | ((uint)f2b(v1.y)<<16);
    pk.w = (uint)f2b(v1.z) | ((uint)f2b(v1.w)<<16);
    *(uint4*)(jb.dst + (size_t)i*8) = pk;
  }
}

// ---------------- GEMM (QKV): C[M,N] = A[M,K] @ W[N,K]^T + bias ----------
// M=4096, N=1024, K=1024. 128x128 tile, BK=32, 256 threads (4 waves, 64x64).
// Staging via global_load_lds (16B/lane, linear LDS dest); XOR swizzle on
// global source col + same XOR on ds_read (rule 21). r4-measured structure.
struct GArg { const ushort_t* A; const ushort_t* W; const float* bias; void* O; };

__global__ __launch_bounds__(256) void gemm_nt(GArg g0, GArg g1, GArg g2)
{
  GArg g = (blockIdx.z==0) ? g0 : ((blockIdx.z==1) ? g1 : g2);
  __shared__ __align__(16) ushort_t As[128*32];
  __shared__ __align__(16) ushort_t Bs[128*32];
  const int tid  = threadIdx.x;
  const int lane = tid & 63;
  const int w    = tid >> 6;
  const int ml   = lane & 15, quad = lane >> 4;

  // XCD-aware block swizzle: 256 wgs per z-slice, 256%8==0 -> bijective.
  int lid = blockIdx.x + 8*blockIdx.y;
  int t   = (lid & 7)*32 + (lid >> 3);
  const int m0 = (t >> 3)*128, n0 = (t & 7)*128;
  const int wm = (w>>1)*64, wn = (w&1)*64;

  const int srow = lane >> 2;                           // 0..15
  const int scol = ((lane & 3) ^ ((lane >> 3) & 3))*8;  // pre-swizzled col
  const int rA0 = w*16, rA1 = 64 + w*16;
  const ushort_t* gA = g.A + (size_t)m0*1024;
  const ushort_t* gB = g.W + (size_t)n0*1024;
  const int sxor = (quad ^ ((ml >> 1) & 3))*8;

  f32x4 acc[4][4];
  #pragma unroll
  for (int i=0;i<4;i++)
    #pragma unroll
    for (int j=0;j<4;j++) acc[i][j]=fz4();

  for (int kt=0; kt<32; ++kt){
    int kof = kt*32 + scol;
    gload16(gA + (size_t)(rA0+srow)*1024 + kof, &As[rA0*32]);
    gload16(gA + (size_t)(rA1+srow)*1024 + kof, &As[rA1*32]);
    gload16(gB + (size_t)(rA0+srow)*1024 + kof, &Bs[rA0*32]);
    gload16(gB + (size_t)(rA1+srow)*1024 + kof, &Bs[rA1*32]);
    __syncthreads();

    bf16x8 af[4], bfr[4];
    #pragma unroll
    for (int t4=0;t4<4;t4++)
      af[t4]  = __builtin_bit_cast(bf16x8, *(const uint4*)&As[(wm + t4*16 + ml)*32 + sxor]);
    #pragma unroll
    for (int t4=0;t4<4;t4++)
      bfr[t4] = __builtin_bit_cast(bf16x8, *(const uint4*)&Bs[(wn + t4*16 + ml)*32 + sxor]);
    #pragma unroll
    for (int ti=0;ti<4;ti++)
      #pragma unroll
      for (int tj=0;tj<4;tj++)
        acc[ti][tj] = __builtin_amdgcn_mfma_f32_16x16x32_bf16(af[ti], bfr[tj], acc[ti][tj], 0,0,0);
    __syncthreads();
  }
  // ---- epilogue: C row=(lane>>4)*4+reg, col=lane&15 (m89-verified) ----
  #pragma unroll
  for (int tj=0;tj<4;tj++){
    int gcol = n0 + wn + tj*16 + ml;
    float bv = g.bias[gcol];
    #pragma unroll
    for (int ti=0;ti<4;ti++){
      int growb = m0 + wm + ti*16 + quad*4;
      #pragma unroll
      for (int r=0;r<4;r++){
        float val = acc[ti][tj][r] + bv;
        ((ushort_t*)g.O)[(size_t)(growb + r)*1024 + gcol] = f2b(val);
      }
    }
  }
}

// ---------------- GEMM (out-proj): O[M,N] = A[M,K] @ W[N,K]^T + bias ------
// 128x64 tile -> 512 wgs = 2 wgs/CU. W fp32 (Wo): f2b folded into B-staging
// (removes the dependent convert#2 launch). A via global_load_lds.
__global__ __launch_bounds__(256) void gemm_out(
    const ushort_t* A, const float* W, const float* bias, float* O)
{
  __shared__ __align__(16) ushort_t As[128*32];
  __shared__ __align__(16) ushort_t Bs[64*32];
  const int tid  = threadIdx.x;
  const int lane = tid & 63;
  const int w    = tid >> 6;
  const int ml   = lane & 15, quad = lane >> 4;

  // grid (16,32): lid in [0,512), 512%8==0 -> bijective XCD swizzle
  int lid = blockIdx.x + 16*blockIdx.y;
  int t   = (lid & 7)*64 + (lid >> 3);
  const int m0 = (t >> 4)*128, n0 = (t & 15)*64;
  const int wm = (w>>1)*64, wn = (w&1)*32;

  const int srow = lane >> 2;
  const int scol = ((lane & 3) ^ ((lane >> 3) & 3))*8;
  const int rA0 = w*16, rA1 = 64 + w*16;
  const ushort_t* gA = A + (size_t)m0*1024;
  const int sxor = (quad ^ ((ml >> 1) & 3))*8;

  // B reg-stage mapping: 256 threads = 64 rows x 4 col-chunks (8 fp32 each)
  const int brow = tid >> 2, bc = tid & 3;
  const int bscol = (bc ^ ((brow >> 1) & 3))*8;   // swizzled LDS col (write side)
  const float* gW = W + (size_t)(n0 + brow)*1024 + bc*8;

  f32x4 acc[4][2];
  #pragma unroll
  for (int i=0;i<4;i++){ acc[i][0]=fz4(); acc[i][1]=fz4(); }

  for (int kt=0; kt<32; ++kt){
    int kof = kt*32 + scol;
    gload16(gA + (size_t)(rA0+srow)*1024 + kof, &As[rA0*32]);
    gload16(gA + (size_t)(rA1+srow)*1024 + kof, &As[rA1*32]);
    {
      const float* gw = gW + kt*32;
      float4 v0 = *(const float4*)gw;
      float4 v1 = *(const float4*)(gw+4);
      uint4 pk;
      pk.x = (uint)f2b(v0.x) | ((uint)f2b(v0.y)<<16);
      pk.y = (uint)f2b(v0.z) | ((uint)f2b(v0.w)<<16);
      pk.z = (uint)f2b(v1.x) | ((uint)f2b(v1.y)<<16);
      pk.w = (uint)f2b(v1.z) | ((uint)f2b(v1.w)<<16);
      *(uint4*)&Bs[brow*32 + bscol] = pk;
    }
    __syncthreads();

    bf16x8 af[4], bfr[2];
    #pragma unroll
    for (int t4=0;t4<4;t4++)
      af[t4]  = __builtin_bit_cast(bf16x8, *(const uint4*)&As[(wm + t4*16 + ml)*32 + sxor]);
    #pragma unroll
    for (int t4=0;t4<2;t4++)
      bfr[t4] = __builtin_bit_cast(bf16x8, *(const uint4*)&Bs[(wn + t4*16 + ml)*32 + sxor]);
    #pragma unroll
    for (int ti=0;ti<4;ti++)
      #pragma unroll
      for (int tj=0;tj<2;tj++)
        acc[ti][tj] = __builtin_amdgcn_mfma_f32_16x16x32_bf16(af[ti], bfr[tj], acc[ti][tj], 0,0,0);
    __syncthreads();
  }
  #pragma unroll
  for (int tj=0;tj<2;tj++){
    int gcol = n0 + wn + tj*16 + ml;
    float bv = bias[gcol];
    #pragma unroll
    for (int ti=0;ti<4;ti++){
      int growb = m0 + wm + ti*16 + quad*4;
      #pragma unroll
      for (int r=0;r<4;r++)
        O[(size_t)(growb + r)*1024 + gcol] = acc[ti][tj][r] + bv;
    }
  }
}

// ---------------- sparse attention ----------------
// wg = (b, h, 32 query rows). 128 threads = 2 waves; wave w owns rows 16w..16w+15.
// Slots: 0..255 strided (j=8*slot), 256..351 local (j = i0-32 + slot-256).
#define SW2 360   // row stride in bf16 elems
__global__ __launch_bounds__(128) void attn_k(
    const ushort_t* Qb, const ushort_t* Kb, const ushort_t* Vb,
    ushort_t* Ctxb, float* attn_out)
{
  __shared__ ushort_t stash[32*SW2];   // unnormalized exp(score), bf16
  __shared__ float invl[32];           // 1 / row-sum
  const int lane = threadIdx.x & 63;
  const int w    = threadIdx.x >> 6;
  const int ml   = lane & 15, quad = lane >> 4;
  // XCD swizzle: 2048 wgs, %8==0 bijective; groups tiles of one (b,h) panel.
  int lid = blockIdx.x + 64*(blockIdx.y + 16*blockIdx.z);
  int tt  = (lid & 7)*256 + (lid >> 3);
  const int tile = tt & 63, h = (tt >> 6) & 15, b = tt >> 10;
  const int i0  = tile*32;
  const int jl0 = i0 - 32;
  const int rb  = 16*w;
  const size_t bh = (size_t)b*2048*1024 + (size_t)h*64;

  // ---- phase 1: scores -> exp -> stash; row-sums ----
  bf16x8 aq0, aq1;
  {
    const ushort_t* qp = Qb + bh + (size_t)(i0 + rb + ml)*1024 + quad*8;
    aq0 = __builtin_bit_cast(bf16x8, *(const uint4*)qp);
    aq1 = __builtin_bit_cast(bf16x8, *(const uint4*)(qp + 32));
  }
  float lsum[4] = {0.f,0.f,0.f,0.f};
  for (int c=0;c<22;c++){
    int j  = (c<16) ? (128*c + 8*ml) : (jl0 + 16*(c-16) + ml);
    int jc = imin(imax(j,0),2047);
    const ushort_t* kp = Kb + bh + (size_t)jc*1024 + quad*8;
    bf16x8 kb0 = __builtin_bit_cast(bf16x8, *(const uint4*)kp);
    bf16x8 kb1 = __builtin_bit_cast(bf16x8, *(const uint4*)(kp + 32));
    f32x4 sc = fz4();
    sc = __builtin_amdgcn_mfma_f32_16x16x32_bf16(aq0, kb0, sc, 0,0,0);
    sc = __builtin_amdgcn_mfma_f32_16x16x32_bf16(aq1, kb1, sc, 0,0,0);
    int slot = 16*c + ml;
    #pragma unroll
    for (int r=0;r<4;r++){
      int rl = rb + quad*4 + r;
      int i  = i0 + rl;
      bool valid = (c<16) ? true :
        ((j>=0) && (j<2048) && ((j&7)!=0) && (j >= i-32) && (j < i+32));
      float e = valid ? __expf(sc[r]*0.125f) : 0.f;   // masked -> exact 0
      ushort_t eb = f2b(e);
      lsum[r] += b2f(eb);                 // sum the ROUNDED values
      stash[rl*SW2 + slot] = eb;
    }
  }
  #pragma unroll
  for (int off=1; off<16; off<<=1){
    #pragma unroll
    for (int r=0;r<4;r++) lsum[r] += __shfl_xor(lsum[r], off);
  }
  if (ml==0){
    #pragma unroll
    for (int r=0;r<4;r++) invl[rb + quad*4 + r] = 1.f / lsum[r];
  }
  // No __syncthreads: each wave only ever touches its own 16 rows.

  // ---- phase 2: coalesced dense attn row writes (512 MB stream; nt) ----
  const size_t arow = ((size_t)(b*16 + h))*2048;
  for (int it=0; it<128; ++it){
    int r     = rb + (it>>3);
    int inner = ((it&7)<<6) + lane;     // 512 float4-groups per row
    int j0    = inner*4;
    float inv  = invl[r];
    float sval = b2f(stash[r*SW2 + (inner>>1)]);      // strided slot (iff inner even)
    int off    = j0 - jl0;                            // local-window offset (mult of 4)
    int offc   = imin(imax(off,0),92);
    uint2 lvu  = *(const uint2*)&stash[r*SW2 + 256 + offc];  // 4 local bf16
    bool lok = (off>=0) && (off<96);
    float lx = lok ? b2f((ushort_t)(lvu.x & 0xffffu)) : 0.f;
    float ly = lok ? b2f((ushort_t)(lvu.x >> 16))     : 0.f;
    float lz = lok ? b2f((ushort_t)(lvu.y & 0xffffu)) : 0.f;
    float lw = lok ? b2f((ushort_t)(lvu.y >> 16))     : 0.f;
    f32x4 o;
    o[0] = ((inner&1)==0) ? inv*sval : inv*lx;        // j%8==0 -> strided value
    o[1] = inv*ly; o[2] = inv*lz; o[3] = inv*lw;
    __builtin_nontemporal_store(o, (f32x4*)&attn_out[(arow + i0 + r)*2048 + j0]);
  }

  // ---- phase 3: PV via MFMA ----
  f32x4 pacc[4];
  #pragma unroll
  for (int nt=0;nt<4;nt++) pacc[nt]=fz4();
  const ushort_t* prow = &stash[(rb + ml)*SW2];
  for (int ck=0; ck<11; ++ck){
    int s0 = ck*32;
    bf16x8 pa = __builtin_bit_cast(bf16x8, *(const uint4*)(prow + s0 + quad*8));
    ushort_t vr[4][8];
    #pragma unroll
    for (int e=0;e<8;e++){
      int s = s0 + quad*8 + e;
      int j = (s<256) ? 8*s : (jl0 + s - 256);
      int jc = imin(imax(j,0),2047);
      const ushort_t* vp = Vb + bh + (size_t)jc*1024 + ml;
      #pragma unroll
      for (int nt=0;nt<4;nt++) vr[nt][e] = vp[nt*16];
    }
    #pragma unroll
    for (int nt=0;nt<4;nt++){
      uint4 pk;
      pk.x = (uint)vr[nt][0] | ((uint)vr[nt][1]<<16);
      pk.y = (uint)vr[nt][2] | ((uint)vr[nt][3]<<16);
      pk.z = (uint)vr[nt][4] | ((uint)vr[nt][5]<<16);
      pk.w = (uint)vr[nt][6] | ((uint)vr[nt][7]<<16);
      bf16x8 bfr = __builtin_bit_cast(bf16x8, pk);
      pacc[nt] = __builtin_amdgcn_mfma_f32_16x16x32_bf16(pa, bfr, pacc[nt], 0,0,0);
    }
  }
  // D layout: row = quad*4+reg (within wave's 16-row tile), col = nt*16+ml
  #pragma unroll
  for (int nt=0;nt<4;nt++){
    #pragma unroll
    for (int rr=0;rr<4;rr++){
      int r = rb + quad*4 + rr;
      float val = pacc[nt][rr] * invl[r];
      Ctxb[bh + (size_t)(i0 + r)*1024 + nt*16 + ml] = f2b(val);
    }
  }
}

extern "C" void kernel_launch(void* const* d_in, const int* in_sizes, int n_in,
                              void* d_out, int out_size, void* d_ws, size_t ws_size,
                              hipStream_t stream) {
  (void)in_sizes; (void)n_in; (void)out_size; (void)ws_size;
  const float* query = (const float*)d_in[0];
  const float* key_  = (const float*)d_in[1];
  const float* value = (const float*)d_in[2];
  const float* Wq = (const float*)d_in[3];
  const float* bq = (const float*)d_in[4];
  const float* Wk = (const float*)d_in[5];
  const float* bk = (const float*)d_in[6];
  const float* Wv = (const float*)d_in[7];
  const float* bv = (const float*)d_in[8];
  const float* Wo = (const float*)d_in[9];
  const float* bo = (const float*)d_in[10];

  // Workspace: exactly 32 MB (Qb/Kb/Vb/Ctxb, bf16 4096x1024 each).
  char* ws = (char*)d_ws;
  ushort_t* Qb   = (ushort_t*)(ws);
  ushort_t* Kb   = (ushort_t*)(ws + (size_t)( 8<<20));
  ushort_t* Vb   = (ushort_t*)(ws + (size_t)(16<<20));
  ushort_t* Ctxb = (ushort_t*)(ws + (size_t)(24<<20));

  float* out = (float*)d_out;
  float* attn_out = out + (size_t)4096*1024;

  // Scratch: the 512 MB attn_out region is dead until attn_k overwrites it.
  ushort_t* scr = (ushort_t*)attn_out;
  ushort_t* Aq  = scr;
  ushort_t* Ak  = scr + (size_t)1*4096*1024;
  ushort_t* Av  = scr + (size_t)2*4096*1024;
  ushort_t* Wqb = scr + (size_t)3*4096*1024;
  ushort_t* Wkb = Wqb + (size_t)1024*1024;
  ushort_t* Wvb = Wkb + (size_t)1024*1024;

  const int NA = 4096*1024/8;   // 524288 vec8 per activation matrix
  const int NW = 1024*1024/8;   // 131072 vec8 per weight matrix

  CJob ja{query, Aq, NA}, jb{key_, Ak, NA}, jc{value, Av, NA};
  CJob jd{Wq, Wqb, NW}, je{Wk, Wkb, NW}, jf{Wv, Wvb, NW};
  convert_k<<<dim3(1024,6), 256, 0, stream>>>(ja, jb, jc, jd, je, jf);

  GArg ga{Aq, Wqb, bq, Qb};
  GArg gb{Ak, Wkb, bk, Kb};
  GArg gc{Av, Wvb, bv, Vb};
  gemm_nt<<<dim3(8,32,3), 256, 0, stream>>>(ga, gb, gc);

  attn_k<<<dim3(64,16,2), 128, 0, stream>>>(Qb, Kb, Vb, Ctxb, attn_out);

  // out-projection: Wo f2b fused into staging (no convert#2 launch)
  gemm_out<<<dim3(16,32), 256, 0, stream>>>(Ctxb, Wo, bo, out);
}